// Round 3
// baseline (121.732 us; speedup 1.0000x reference)
//
#include <hip/hip_runtime.h>

// out[1024][1024] = relu(a @ feats^T) @ relu(b @ feats^T)^T ; fp32 in/out.
// SINGLE fused kernel (grid=256 blocks == #CUs, all co-resident) with
// device-scope arrival barriers between phases:
//   Phase A: [a;b] @ feats^T, split-K(8) -> fp32 partials in d_ws
//   Phase B: reduce 8 partials + relu + cvt -> bf16 fk[2048][128]
//   Phase C: fk_a @ fk_b^T (MFMA) -> out
// Rationale: R2 showed 3 dependent dispatches cost ~20+ us in launch gaps;
// kernel bodies are ~10 us of real work. One dispatch removes the gaps.

typedef __attribute__((ext_vector_type(8))) __bf16 bf16x8;
typedef __attribute__((ext_vector_type(4))) __bf16 bf16x4;
typedef __attribute__((ext_vector_type(2))) __bf16 bf16x2;
typedef __attribute__((ext_vector_type(4))) float floatx4;

#define KD     2048
#define NF     128
#define NA     1024
#define NPART  8
#define KSPLIT 256          // KD / NPART
#define FKN    (2048 * 128)
#define NBLK   256          // == #CUs; co-residency by capacity (34.9KB LDS, 8 waves)

static __device__ inline bf16x4 cvt4(float4 u) {
    bf16x4 s;
    s[0] = (__bf16)u.x; s[1] = (__bf16)u.y; s[2] = (__bf16)u.z; s[3] = (__bf16)u.w;
    return s;
}
static __device__ inline bf16x8 cvt8(float4 u, float4 v) {
    bf16x8 s;
    s[0] = (__bf16)u.x; s[1] = (__bf16)u.y; s[2] = (__bf16)u.z; s[3] = (__bf16)u.w;
    s[4] = (__bf16)v.x; s[5] = (__bf16)v.y; s[6] = (__bf16)v.z; s[7] = (__bf16)v.w;
    return s;
}

static __device__ inline void grid_barrier(unsigned* ctr) {
    __syncthreads();                    // all block stores drained (barrier implies vmcnt(0))
    if (threadIdx.x == 0) {
        __threadfence();                // release: flush this XCD's L2 to coherent point
        atomicAdd(ctr, 1u);            // device-scope arrive
        while (__hip_atomic_load(ctr, __ATOMIC_RELAXED, __HIP_MEMORY_SCOPE_AGENT) < NBLK)
            __builtin_amdgcn_s_sleep(2);
        __threadfence();                // acquire: invalidate stale lines
    }
    __syncthreads();
}

union SMem {
    struct { __bf16 Xs[64 * 40];  __bf16 Fs[128 * 40]; } a;   // phase A: 15.4 KB
    struct { __bf16 Ps[64 * 136]; __bf16 Qs[64 * 136]; } c;   // phase C: 34.8 KB
};

__global__ __launch_bounds__(512) void fused(const float* __restrict__ A,
                                             const float* __restrict__ B,
                                             const float* __restrict__ F,
                                             float* __restrict__ part,
                                             __bf16* __restrict__ fkb,
                                             float* __restrict__ out,
                                             unsigned* __restrict__ ctr) {
    __shared__ SMem sm;
    const int t    = threadIdx.x;
    const int b    = blockIdx.x;
    const int lane = t & 63;
    const int w    = t >> 6;            // 8 waves
    const int ln   = lane & 15;
    const int quad = lane >> 4;
    const int q8   = quad * 8;

    // ---------------- Phase A: partials = X-tile @ feats-slice^T ----------------
    {
        const int mtile = b & 31;       // 32 row-tiles of 64 over [a;b]
        const int split = b >> 5;       // 8 K-splits of 256
        const int m0    = mtile * 64;
        const int k0    = split * KSPLIT;
        const float* src = (m0 < NA) ? (A + (size_t)m0 * KD)
                                     : (B + (size_t)(m0 - NA) * KD);

        floatx4 acc[4];
#pragma unroll
        for (int mt = 0; mt < 4; mt++) acc[mt] = (floatx4){0.f, 0.f, 0.f, 0.f};

        const int xrow = t >> 3, xcol = (t & 7) * 4;   // 64 x 32 fp32, 1 float4/thread
        const int frow = t >> 2, fcol = (t & 3) * 8;   // 128 x 32 fp32, 2 float4/thread

        for (int kk = 0; kk < KSPLIT; kk += 32) {
            {
                float4 u = *(const float4*)(src + (size_t)xrow * KD + (k0 + kk + xcol));
                *(bf16x4*)&sm.a.Xs[xrow * 40 + xcol] = cvt4(u);
            }
            {
                const float* p = F + (size_t)frow * KD + (k0 + kk + fcol);
                float4 u = *(const float4*)p;
                float4 v = *(const float4*)(p + 4);
                *(bf16x8*)&sm.a.Fs[frow * 40 + fcol] = cvt8(u, v);
            }
            __syncthreads();

            bf16x8 bfrag = *(const bf16x8*)&sm.a.Fs[(w * 16 + ln) * 40 + q8];
#pragma unroll
            for (int mt = 0; mt < 4; mt++) {
                bf16x8 af = *(const bf16x8*)&sm.a.Xs[(mt * 16 + ln) * 40 + q8];
                acc[mt] = __builtin_amdgcn_mfma_f32_16x16x32_bf16(af, bfrag, acc[mt], 0, 0, 0);
            }
            __syncthreads();
        }

        float* pdst = part + (size_t)split * FKN;
        const int col = w * 16 + ln;
#pragma unroll
        for (int mt = 0; mt < 4; mt++)
#pragma unroll
            for (int r = 0; r < 4; r++)
                pdst[(size_t)(m0 + mt * 16 + quad * 4 + r) * NF + col] = acc[mt][r];
    }

    grid_barrier(ctr);

    // ---------------- Phase B: fkb = bf16(relu(sum_s part[s])) ----------------
    {
        size_t base = ((size_t)b << 10) + (size_t)t * 2;   // 1024 elems/block, 2/thread
        float sx = 0.f, sy = 0.f;
#pragma unroll
        for (int s = 0; s < NPART; s++) {
            float2 u = *(const float2*)(part + (size_t)s * FKN + base);
            sx += u.x; sy += u.y;
        }
        bf16x2 o;
        o[0] = (__bf16)fmaxf(sx, 0.f);
        o[1] = (__bf16)fmaxf(sy, 0.f);
        *(bf16x2*)(fkb + base) = o;
    }

    grid_barrier(ctr + 32);

    // ---------------- Phase C: out = fk_a @ fk_b^T ----------------
    {
        const int i0 = (b >> 4) * 64;   // a-row tile
        const int j0 = (b & 15) * 64;   // b-row tile
        const int wm = w & 1;           // 2 m-waves x 4 n-waves
        const int wn = w >> 1;

        const int prow = t >> 3, pcol = (t & 7) * 16;   // 64 x 128 bf16, 32B/thread
        {
            const __bf16* p = fkb + (size_t)(i0 + prow) * NF + pcol;
            const __bf16* q = fkb + (size_t)(NA + j0 + prow) * NF + pcol;
            *(bf16x8*)&sm.c.Ps[prow * 136 + pcol]     = *(const bf16x8*)p;
            *(bf16x8*)&sm.c.Ps[prow * 136 + pcol + 8] = *(const bf16x8*)(p + 8);
            *(bf16x8*)&sm.c.Qs[prow * 136 + pcol]     = *(const bf16x8*)q;
            *(bf16x8*)&sm.c.Qs[prow * 136 + pcol + 8] = *(const bf16x8*)(q + 8);
        }
        __syncthreads();

        floatx4 acc[2];
#pragma unroll
        for (int mt = 0; mt < 2; mt++) acc[mt] = (floatx4){0.f, 0.f, 0.f, 0.f};

#pragma unroll
        for (int k0 = 0; k0 < NF; k0 += 32) {
            bf16x8 bf = *(const bf16x8*)&sm.c.Qs[(wn * 16 + ln) * 136 + k0 + q8];
#pragma unroll
            for (int mt = 0; mt < 2; mt++) {
                bf16x8 af = *(const bf16x8*)&sm.c.Ps[(wm * 32 + mt * 16 + ln) * 136 + k0 + q8];
                acc[mt] = __builtin_amdgcn_mfma_f32_16x16x32_bf16(af, bf, acc[mt], 0, 0, 0);
            }
        }

#pragma unroll
        for (int mt = 0; mt < 2; mt++)
#pragma unroll
            for (int r = 0; r < 4; r++) {
                int row = i0 + wm * 32 + mt * 16 + quad * 4 + r;
                int col = j0 + wn * 16 + ln;
                out[(size_t)row * 1024 + col] = acc[mt][r];
            }
    }
}

extern "C" void kernel_launch(void* const* d_in, const int* in_sizes, int n_in,
                              void* d_out, int out_size, void* d_ws, size_t ws_size,
                              hipStream_t stream) {
    const float* a     = (const float*)d_in[0];
    const float* b     = (const float*)d_in[1];
    const float* feats = (const float*)d_in[2];
    float* out = (float*)d_out;

    float*    part = (float*)d_ws;                                   // 8 MB fp32 partials
    __bf16*   fkb  = (__bf16*)((char*)d_ws + (size_t)NPART * FKN * 4); // 512 KB bf16
    unsigned* ctr  = (unsigned*)((char*)d_ws + (size_t)NPART * FKN * 4 + (size_t)FKN * 2);

    hipMemsetAsync(ctr, 0, 256, stream);   // zero both barrier counters (graph-capturable)
    fused<<<NBLK, 512, 0, stream>>>(a, b, feats, part, fkb, out, ctr);
}

// Round 4
// 107.765 us; speedup vs baseline: 1.1296x; 1.1296x over previous
//
#include <hip/hip_runtime.h>

// out[1024][1024] = relu(a @ feats^T) @ relu(b @ feats^T)^T ; fp32 in/out.
// SINGLE fused kernel (grid=256 blocks == #CUs, co-resident by capacity):
//   Phase A: [a;b] @ feats^T, split-K(8) -> fp32 partials in d_ws
//   Phase B: reduce 8 partials + relu + cvt -> bf16 fk[2048][128]
//   Phase C: fk_a @ fk_b^T (MFMA) -> out
// R3 lesson: flat 256-way atomic barrier w/ all-blocks polling one line cost
// ~25us each (spin congestion). R4: hierarchical arrivals (16 sub-ctrs ->
// root), ONE poller on root, 255 blocks poll a separate read-only flag line
// at ~0.8us intervals.

typedef __attribute__((ext_vector_type(8))) __bf16 bf16x8;
typedef __attribute__((ext_vector_type(4))) __bf16 bf16x4;
typedef __attribute__((ext_vector_type(2))) __bf16 bf16x2;
typedef __attribute__((ext_vector_type(4))) float floatx4;

#define KD     2048
#define NF     128
#define NA     1024
#define NPART  8
#define KSPLIT 256          // KD / NPART
#define FKN    (2048 * 128)
#define NBLK   256          // == #CUs
#define GRPSZ  16
#define NGRP   (NBLK / GRPSZ)   // 16
#define BARWORDS 640        // words per barrier set (sub[16*32] + root[32] + flag[32] + pad)

static __device__ inline bf16x4 cvt4(float4 u) {
    bf16x4 s;
    s[0] = (__bf16)u.x; s[1] = (__bf16)u.y; s[2] = (__bf16)u.z; s[3] = (__bf16)u.w;
    return s;
}
static __device__ inline bf16x8 cvt8(float4 u, float4 v) {
    bf16x8 s;
    s[0] = (__bf16)u.x; s[1] = (__bf16)u.y; s[2] = (__bf16)u.z; s[3] = (__bf16)u.w;
    s[4] = (__bf16)v.x; s[5] = (__bf16)v.y; s[6] = (__bf16)v.z; s[7] = (__bf16)v.w;
    return s;
}

// Hierarchical grid barrier. bar layout (uint words, 128B-spaced lines):
//   bar[g*32]          g-th sub-counter (16 blocks each)
//   bar[NGRP*32]       root counter (16 group-leaders)
//   bar[(NGRP+1)*32]   broadcast flag
static __device__ inline void grid_barrier(unsigned* bar) {
    __syncthreads();                       // all block stores drained (vmcnt0 at s_barrier)
    if (threadIdx.x == 0) {
        __threadfence();                   // release: L2 writeback to coherence point
        const unsigned g = blockIdx.x >> 4;
        bool releaser = false;
        unsigned r = __hip_atomic_fetch_add(&bar[g * 32], 1u,
                         __ATOMIC_RELAXED, __HIP_MEMORY_SCOPE_AGENT);
        if (r == GRPSZ - 1) {              // last arriver of this group
            unsigned rr = __hip_atomic_fetch_add(&bar[NGRP * 32], 1u,
                              __ATOMIC_RELAXED, __HIP_MEMORY_SCOPE_AGENT);
            if (rr == NGRP - 1) {          // last group: release everyone
                __hip_atomic_store(&bar[(NGRP + 1) * 32], 1u,
                                   __ATOMIC_RELAXED, __HIP_MEMORY_SCOPE_AGENT);
                releaser = true;
            }
        }
        if (!releaser) {
            while (__hip_atomic_load(&bar[(NGRP + 1) * 32],
                       __ATOMIC_RELAXED, __HIP_MEMORY_SCOPE_AGENT) == 0)
                __builtin_amdgcn_s_sleep(16);   // ~1k cyc between polls
        }
        __threadfence();                   // acquire: invalidate stale lines
    }
    __syncthreads();
}

union SMem {
    struct { __bf16 Xs[64 * 40];  __bf16 Fs[128 * 40]; } a;   // phase A: 15.4 KB
    struct { __bf16 Ps[64 * 136]; __bf16 Qs[64 * 136]; } c;   // phase C: 34.8 KB
};

__global__ __launch_bounds__(512) void fused(const float* __restrict__ A,
                                             const float* __restrict__ B,
                                             const float* __restrict__ F,
                                             float* __restrict__ part,
                                             __bf16* __restrict__ fkb,
                                             float* __restrict__ out,
                                             unsigned* __restrict__ bar) {
    __shared__ SMem sm;
    const int t    = threadIdx.x;
    const int b    = blockIdx.x;
    const int lane = t & 63;
    const int w    = t >> 6;            // 8 waves
    const int ln   = lane & 15;
    const int quad = lane >> 4;
    const int q8   = quad * 8;

    // ---------------- Phase A: partials = X-tile @ feats-slice^T ----------------
    {
        const int mtile = b & 31;       // 32 row-tiles of 64 over [a;b]
        const int split = b >> 5;       // 8 K-splits of 256
        const int m0    = mtile * 64;
        const int k0    = split * KSPLIT;
        const float* src = (m0 < NA) ? (A + (size_t)m0 * KD)
                                     : (B + (size_t)(m0 - NA) * KD);

        floatx4 acc[4];
#pragma unroll
        for (int mt = 0; mt < 4; mt++) acc[mt] = (floatx4){0.f, 0.f, 0.f, 0.f};

        const int xrow = t >> 3, xcol = (t & 7) * 4;   // 64 x 32 fp32
        const int frow = t >> 2, fcol = (t & 3) * 8;   // 128 x 32 fp32

        for (int kk = 0; kk < KSPLIT; kk += 32) {
            {
                float4 u = *(const float4*)(src + (size_t)xrow * KD + (k0 + kk + xcol));
                *(bf16x4*)&sm.a.Xs[xrow * 40 + xcol] = cvt4(u);
            }
            {
                const float* p = F + (size_t)frow * KD + (k0 + kk + fcol);
                float4 u = *(const float4*)p;
                float4 v = *(const float4*)(p + 4);
                *(bf16x8*)&sm.a.Fs[frow * 40 + fcol] = cvt8(u, v);
            }
            __syncthreads();

            bf16x8 bfrag = *(const bf16x8*)&sm.a.Fs[(w * 16 + ln) * 40 + q8];
#pragma unroll
            for (int mt = 0; mt < 4; mt++) {
                bf16x8 af = *(const bf16x8*)&sm.a.Xs[(mt * 16 + ln) * 40 + q8];
                acc[mt] = __builtin_amdgcn_mfma_f32_16x16x32_bf16(af, bfrag, acc[mt], 0, 0, 0);
            }
            __syncthreads();
        }

        float* pdst = part + (size_t)split * FKN;
        const int col = w * 16 + ln;
#pragma unroll
        for (int mt = 0; mt < 4; mt++)
#pragma unroll
            for (int r = 0; r < 4; r++)
                pdst[(size_t)(m0 + mt * 16 + quad * 4 + r) * NF + col] = acc[mt][r];
    }

    grid_barrier(bar);

    // ---------------- Phase B: fkb = bf16(relu(sum_s part[s])) ----------------
    {
        size_t base = ((size_t)b << 10) + (size_t)t * 2;   // 1024 elems/block
        float sx = 0.f, sy = 0.f;
#pragma unroll
        for (int s = 0; s < NPART; s++) {
            float2 u = *(const float2*)(part + (size_t)s * FKN + base);
            sx += u.x; sy += u.y;
        }
        bf16x2 o;
        o[0] = (__bf16)fmaxf(sx, 0.f);
        o[1] = (__bf16)fmaxf(sy, 0.f);
        *(bf16x2*)(fkb + base) = o;
    }

    grid_barrier(bar + BARWORDS);

    // ---------------- Phase C: out = fk_a @ fk_b^T ----------------
    {
        const int i0 = (b >> 4) * 64;   // a-row tile
        const int j0 = (b & 15) * 64;   // b-row tile
        const int wm = w & 1;           // 2 m-waves x 4 n-waves
        const int wn = w >> 1;

        const int prow = t >> 3, pcol = (t & 7) * 16;   // 64 x 128 bf16
        {
            const __bf16* p = fkb + (size_t)(i0 + prow) * NF + pcol;
            const __bf16* q = fkb + (size_t)(NA + j0 + prow) * NF + pcol;
            *(bf16x8*)&sm.c.Ps[prow * 136 + pcol]     = *(const bf16x8*)p;
            *(bf16x8*)&sm.c.Ps[prow * 136 + pcol + 8] = *(const bf16x8*)(p + 8);
            *(bf16x8*)&sm.c.Qs[prow * 136 + pcol]     = *(const bf16x8*)q;
            *(bf16x8*)&sm.c.Qs[prow * 136 + pcol + 8] = *(const bf16x8*)(q + 8);
        }
        __syncthreads();

        floatx4 acc[2];
#pragma unroll
        for (int mt = 0; mt < 2; mt++) acc[mt] = (floatx4){0.f, 0.f, 0.f, 0.f};

#pragma unroll
        for (int k0 = 0; k0 < NF; k0 += 32) {
            bf16x8 bf = *(const bf16x8*)&sm.c.Qs[(wn * 16 + ln) * 136 + k0 + q8];
#pragma unroll
            for (int mt = 0; mt < 2; mt++) {
                bf16x8 af = *(const bf16x8*)&sm.c.Ps[(wm * 32 + mt * 16 + ln) * 136 + k0 + q8];
                acc[mt] = __builtin_amdgcn_mfma_f32_16x16x32_bf16(af, bf, acc[mt], 0, 0, 0);
            }
        }

#pragma unroll
        for (int mt = 0; mt < 2; mt++)
#pragma unroll
            for (int r = 0; r < 4; r++) {
                int row = i0 + wm * 32 + mt * 16 + quad * 4 + r;
                int col = j0 + wn * 16 + ln;
                out[(size_t)row * 1024 + col] = acc[mt][r];
            }
    }
}

extern "C" void kernel_launch(void* const* d_in, const int* in_sizes, int n_in,
                              void* d_out, int out_size, void* d_ws, size_t ws_size,
                              hipStream_t stream) {
    const float* a     = (const float*)d_in[0];
    const float* b     = (const float*)d_in[1];
    const float* feats = (const float*)d_in[2];
    float* out = (float*)d_out;

    float*    part = (float*)d_ws;                                     // 8 MB fp32 partials
    __bf16*   fkb  = (__bf16*)((char*)d_ws + (size_t)NPART * FKN * 4); // 512 KB bf16
    unsigned* bar  = (unsigned*)((char*)d_ws + (size_t)NPART * FKN * 4 + (size_t)FKN * 2);

    hipMemsetAsync(bar, 0, 8192, stream);   // zero both barrier sets
    fused<<<NBLK, 512, 0, stream>>>(a, b, feats, part, fkb, out, bar);
}

// Round 5
// 87.415 us; speedup vs baseline: 1.3926x; 1.2328x over previous
//
#include <hip/hip_runtime.h>

// out[1024][1024] = relu(a @ feats^T) @ relu(b @ feats^T)^T ; fp32 in/out.
// 3 dispatches, NO LDS, NO grid barriers (R3/R4 showed device-scope barriers
// cost ~18us each; dispatch gaps are ~2us):
//   gemm1      : [a;b] @ feats^T split-K(16) -> fp32 partials (direct-from-
//                global MFMA fragment loads, L1 serves 4-way intra-block reuse)
//   reduce_relu: sum 16 partials + relu + cvt -> bf16 fk[2048][128]
//   gemm2      : fk_a @ fk_b^T -> out (direct fragment loads again)

typedef __attribute__((ext_vector_type(8))) __bf16 bf16x8;
typedef __attribute__((ext_vector_type(4))) __bf16 bf16x4;
typedef __attribute__((ext_vector_type(4))) float floatx4;

#define KD     2048
#define NF     128
#define NA     1024
#define NPART  16
#define KSPLIT 128          // KD / NPART
#define FKN    (2048 * 128)

// load 8 consecutive fp32 and pack to bf16x8 (A/B fragment for 16x16x32)
static __device__ inline bf16x8 ldcvt8(const float* __restrict__ p) {
    float4 u = *(const float4*)p;
    float4 v = *(const float4*)(p + 4);
    bf16x8 s;
    s[0] = (__bf16)u.x; s[1] = (__bf16)u.y; s[2] = (__bf16)u.z; s[3] = (__bf16)u.w;
    s[4] = (__bf16)v.x; s[5] = (__bf16)v.y; s[6] = (__bf16)v.z; s[7] = (__bf16)v.w;
    return s;
}

// ---- gemm1: part[s][2048][128] = X[m, s*128:(s+1)*128] @ feats[:, same]^T ----
// grid (32, 16): x = 64-row tile of [a;b], y = K-split. 256 thr = 4 waves;
// wave w owns feat cols [w*32, w*32+32). A-frags shared by all 4 waves (L1).
__global__ __launch_bounds__(256) void gemm1(const float* __restrict__ A,
                                             const float* __restrict__ B,
                                             const float* __restrict__ F,
                                             float* __restrict__ part) {
    const int t    = threadIdx.x;
    const int lane = t & 63;
    const int w    = t >> 6;
    const int ln   = lane & 15;
    const int quad = lane >> 4;
    const int q8   = quad * 8;

    const int m0 = blockIdx.x * 64;
    const int s  = blockIdx.y;
    const int k0 = s * KSPLIT;
    const float* src = (m0 < NA) ? (A + (size_t)m0 * KD)
                                 : (B + (size_t)(m0 - NA) * KD);

    floatx4 acc[4][2];
#pragma unroll
    for (int mt = 0; mt < 4; mt++)
#pragma unroll
        for (int nt = 0; nt < 2; nt++)
            acc[mt][nt] = (floatx4){0.f, 0.f, 0.f, 0.f};

#pragma unroll
    for (int kk = 0; kk < KSPLIT; kk += 32) {
        const int kb = k0 + kk + q8;       // lane's k-offset for this chunk
        bf16x8 bfrag[2];
#pragma unroll
        for (int nt = 0; nt < 2; nt++)
            bfrag[nt] = ldcvt8(F + (size_t)(w * 32 + nt * 16 + ln) * KD + kb);
#pragma unroll
        for (int mt = 0; mt < 4; mt++) {
            bf16x8 af = ldcvt8(src + (size_t)(mt * 16 + ln) * KD + kb);
#pragma unroll
            for (int nt = 0; nt < 2; nt++)
                acc[mt][nt] = __builtin_amdgcn_mfma_f32_16x16x32_bf16(
                    af, bfrag[nt], acc[mt][nt], 0, 0, 0);
        }
    }

    float* pdst = part + (size_t)s * FKN;
#pragma unroll
    for (int mt = 0; mt < 4; mt++)
#pragma unroll
        for (int nt = 0; nt < 2; nt++)
#pragma unroll
            for (int r = 0; r < 4; r++)
                pdst[(size_t)(m0 + mt * 16 + quad * 4 + r) * NF
                     + (w * 32 + nt * 16 + ln)] = acc[mt][nt][r];
}

// ---- reduce_relu: fkb[i] = bf16(relu(sum_s part[s][i])) ----
__global__ __launch_bounds__(256) void reduce_relu(const float* __restrict__ part,
                                                   __bf16* __restrict__ fkb) {
    int idx = blockIdx.x * 256 + threadIdx.x;   // 65536 threads, 4 floats each
    size_t base = (size_t)idx * 4;
    float4 sum = make_float4(0.f, 0.f, 0.f, 0.f);
#pragma unroll
    for (int s = 0; s < NPART; s++) {
        float4 u = *(const float4*)(part + (size_t)s * FKN + base);
        sum.x += u.x; sum.y += u.y; sum.z += u.z; sum.w += u.w;
    }
    bf16x4 o;
    o[0] = (__bf16)fmaxf(sum.x, 0.f);
    o[1] = (__bf16)fmaxf(sum.y, 0.f);
    o[2] = (__bf16)fmaxf(sum.z, 0.f);
    o[3] = (__bf16)fmaxf(sum.w, 0.f);
    *(bf16x4*)(fkb + base) = o;
}

// ---- gemm2: out[i][j] = sum_f fkb[i][f] * fkb[1024+j][f] ----
// grid (16,16): 64x64 out tiles; 4 waves in 2x2; frags direct from global.
__global__ __launch_bounds__(256) void gemm2(const __bf16* __restrict__ fkb,
                                             float* __restrict__ out) {
    const int t    = threadIdx.x;
    const int lane = t & 63;
    const int w    = t >> 6;
    const int wm   = w & 1;
    const int wn   = w >> 1;
    const int ln   = lane & 15;
    const int quad = lane >> 4;
    const int q8   = quad * 8;

    const int i0 = blockIdx.y * 64;
    const int j0 = blockIdx.x * 64;

    floatx4 acc[2][2];
#pragma unroll
    for (int mt = 0; mt < 2; mt++)
#pragma unroll
        for (int nt = 0; nt < 2; nt++)
            acc[mt][nt] = (floatx4){0.f, 0.f, 0.f, 0.f};

#pragma unroll
    for (int k0 = 0; k0 < NF; k0 += 32) {
        bf16x8 af[2], bf[2];
#pragma unroll
        for (int mt = 0; mt < 2; mt++)
            af[mt] = *(const bf16x8*)(fkb + (size_t)(i0 + wm * 32 + mt * 16 + ln) * NF
                                      + k0 + q8);
#pragma unroll
        for (int nt = 0; nt < 2; nt++)
            bf[nt] = *(const bf16x8*)(fkb + (size_t)(NA + j0 + wn * 32 + nt * 16 + ln) * NF
                                      + k0 + q8);
#pragma unroll
        for (int mt = 0; mt < 2; mt++)
#pragma unroll
            for (int nt = 0; nt < 2; nt++)
                acc[mt][nt] = __builtin_amdgcn_mfma_f32_16x16x32_bf16(
                    af[mt], bf[nt], acc[mt][nt], 0, 0, 0);
    }

#pragma unroll
    for (int mt = 0; mt < 2; mt++)
#pragma unroll
        for (int nt = 0; nt < 2; nt++)
#pragma unroll
            for (int r = 0; r < 4; r++) {
                int row = i0 + wm * 32 + mt * 16 + quad * 4 + r;
                int col = j0 + wn * 32 + nt * 16 + ln;
                out[(size_t)row * 1024 + col] = acc[mt][nt][r];
            }
}

extern "C" void kernel_launch(void* const* d_in, const int* in_sizes, int n_in,
                              void* d_out, int out_size, void* d_ws, size_t ws_size,
                              hipStream_t stream) {
    const float* a     = (const float*)d_in[0];
    const float* b     = (const float*)d_in[1];
    const float* feats = (const float*)d_in[2];
    float* out = (float*)d_out;

    float*  part = (float*)d_ws;                                      // 16 MB fp32
    __bf16* fkb  = (__bf16*)((char*)d_ws + (size_t)NPART * FKN * 4);  // 512 KB bf16

    gemm1<<<dim3(32, NPART), 256, 0, stream>>>(a, b, feats, part);
    reduce_relu<<<256, 256, 0, stream>>>(part, fkb);
    gemm2<<<dim3(16, 16), 256, 0, stream>>>(fkb, out);
}